// Round 5
// baseline (485.709 us; speedup 1.0000x reference)
//
#include <hip/hip_runtime.h>
#include <stdint.h>

#define TT 8192          // sequence length T
#define BT 16384         // B*T tokens
#define MCH 4096         // token chunk for qkv GEMM + attention

typedef __attribute__((ext_vector_type(8))) __bf16 bf16x8;
typedef __attribute__((ext_vector_type(4))) float floatx4;

__device__ __forceinline__ float bf2f(unsigned short h) {
  union { unsigned u; float f; } x; x.u = ((unsigned)h) << 16; return x.f;
}
__device__ __forceinline__ unsigned short f2bf(float f) {
  union { float f; unsigned u; } x; x.f = f;
  unsigned r = (x.u + 0x7fffu + ((x.u >> 16) & 1u)) >> 16;
  return (unsigned short)r;
}

// ---------------------------------------------------------------------------
// Stage one 128x32 tile (row stride K elements) into LDS [128][40] bf16.
// 256 threads: row = tid>>1, half = tid&1 (16 elements each).
// F32 path converts fp32 -> bf16 (round-to-nearest-even) in flight.
// Stride 40 (+8 pad) keeps ds_write_b128/ds_read_b128 at uniform
// 8-accesses-per-bank (the wave64-b128 minimum) => conflict-free.
// ---------------------------------------------------------------------------
template <bool F32>
__device__ __forceinline__ void stage_tile(const void* __restrict__ src, int K,
                                           int kt, unsigned short* lds, int tid) {
  const int row  = tid >> 1;
  const int half = tid & 1;
  unsigned short tmp[16];
  if (F32) {
    const float* g = (const float*)src + (size_t)row * K + kt + half * 16;
#pragma unroll
    for (int q = 0; q < 4; ++q) {
      const float4 f = ((const float4*)g)[q];
      tmp[q * 4 + 0] = f2bf(f.x);
      tmp[q * 4 + 1] = f2bf(f.y);
      tmp[q * 4 + 2] = f2bf(f.z);
      tmp[q * 4 + 3] = f2bf(f.w);
    }
  } else {
    const unsigned short* g = (const unsigned short*)src + (size_t)row * K + kt + half * 16;
    *(uint4*)&tmp[0] = ((const uint4*)g)[0];
    *(uint4*)&tmp[8] = ((const uint4*)g)[1];
  }
  unsigned short* d = lds + row * 40 + half * 16;
  ((uint4*)d)[0] = *(uint4*)&tmp[0];
  ((uint4*)d)[1] = *(uint4*)&tmp[8];
}

// ---------------------------------------------------------------------------
// GEMM: C[M,N] = A[M,K] . W[N,K]^T   (fp32 or bf16 in; bf16 OR fp32 out;
// fp32 accumulate). 128x128 tile, 4 waves (2x2), each wave 64x64 via 4x4
// mfma_f32_16x16x32_bf16.
// ---------------------------------------------------------------------------
template <bool AF32, bool WF32, bool CF32>
__global__ __launch_bounds__(256) void gemm_bt(
    const void* __restrict__ A,
    const void* __restrict__ W,
    void* __restrict__ C,
    int M, int N, int K)
{
  __shared__ __align__(16) unsigned short As[128 * 40];
  __shared__ __align__(16) unsigned short Bs[128 * 40];

  const int tid  = threadIdx.x;
  const int lane = tid & 63;
  const int w    = tid >> 6;
  const int nb   = N / 128;
  const int bm   = blockIdx.x / nb;
  const int bn   = blockIdx.x % nb;
  const int wm   = w & 1;
  const int wn   = w >> 1;
  const int kg   = lane >> 4;   // k-chunk group 0..3 (8 bf16 each)
  const int lm   = lane & 15;

  floatx4 acc[4][4];
  floatx4 z = {0.f, 0.f, 0.f, 0.f};
#pragma unroll
  for (int i = 0; i < 4; ++i)
#pragma unroll
    for (int j = 0; j < 4; ++j) acc[i][j] = z;

  const size_t abase = (size_t)(bm * 128) * K;
  const size_t bbase = (size_t)(bn * 128) * K;
  const void* Ap = AF32 ? (const void*)((const float*)A + abase)
                        : (const void*)((const unsigned short*)A + abase);
  const void* Wp = WF32 ? (const void*)((const float*)W + bbase)
                        : (const void*)((const unsigned short*)W + bbase);

  for (int kt = 0; kt < K; kt += 32) {
    stage_tile<AF32>(Ap, K, kt, As, tid);
    stage_tile<WF32>(Wp, K, kt, Bs, tid);
    __syncthreads();

    bf16x8 af[4], bfr[4];
#pragma unroll
    for (int i = 0; i < 4; ++i) {
      const int r = wm * 64 + i * 16 + lm;
      af[i] = *(const bf16x8*)(As + r * 40 + kg * 8);
    }
#pragma unroll
    for (int j = 0; j < 4; ++j) {
      const int r = wn * 64 + j * 16 + lm;
      bfr[j] = *(const bf16x8*)(Bs + r * 40 + kg * 8);
    }
#pragma unroll
    for (int i = 0; i < 4; ++i)
#pragma unroll
      for (int j = 0; j < 4; ++j)
        acc[i][j] = __builtin_amdgcn_mfma_f32_16x16x32_bf16(af[i], bfr[j], acc[i][j], 0, 0, 0);
    __syncthreads();
  }

  // C/D layout: col = lane&15, row = (lane>>4)*4 + reg
#pragma unroll
  for (int i = 0; i < 4; ++i) {
    const int row0 = bm * 128 + wm * 64 + i * 16 + kg * 4;
#pragma unroll
    for (int j = 0; j < 4; ++j) {
      const int col = bn * 128 + wn * 64 + j * 16 + lm;
#pragma unroll
      for (int r = 0; r < 4; ++r) {
        if (CF32)
          ((float*)C)[(size_t)(row0 + r) * N + col] = acc[i][j][r];
        else
          ((unsigned short*)C)[(size_t)(row0 + r) * N + col] = f2bf(acc[i][j][r]);
      }
    }
  }
}

// ---------------------------------------------------------------------------
// Per-token head-attention with fused RoPE (sin/cos computed inline).
// One wave per token (2 tokens / 128-thread block).
// qkv row (3072 bf16) -> LDS fp32 (stride 68 pads banks), rope on q,k.
// scores 16x16 (scale 1/8) -> softmax -> PV (16x64).
// Output written directly in the transpose(0,2,1,3).reshape layout:
//   Y[b*8192 + qh*512 + t/16][(t&15)*64 + d]
// ---------------------------------------------------------------------------
__global__ __launch_bounds__(128) void attn_rope_k(
    const unsigned short* __restrict__ qkv,   // chunk-local, MCH tokens
    unsigned short* __restrict__ Y,
    int base)                                  // global token offset of chunk
{
  __shared__ float sQ[2][16 * 68];
  __shared__ float sK[2][16 * 68];
  __shared__ float sV[2][16 * 68];
  __shared__ float sP[2][256];   // P^T: [kh*16 + qh]

  const int wave = threadIdx.x >> 6;
  const int lane = threadIdx.x & 63;
  const int ml = blockIdx.x * 2 + wave;  // chunk-local token
  const int m  = base + ml;              // global token
  const int t  = m & (TT - 1);
  const int b  = m >> 13;

  float* Q  = sQ[wave];
  float* Kx = sK[wave];
  float* V  = sV[wave];
  float* P  = sP[wave];

  const uint4* row = (const uint4*)(qkv + (size_t)ml * 3072);
#pragma unroll
  for (int i = 0; i < 6; ++i) {
    const int c = lane + 64 * i;          // chunk of 8 bf16, 0..383
    union { uint4 u4; unsigned short s[8]; } cv;
    cv.u4 = row[c];
    float f[8];
#pragma unroll
    for (int j = 0; j < 8; ++j) f[j] = bf2f(cv.s[j]);
    const int n0   = c * 8;
    const int part = n0 >> 10;            // 0=q 1=k 2=v (uniform per i)
    const int h    = (n0 >> 6) & 15;
    const int d0   = n0 & 63;
    if (part < 2) {
#pragma unroll
      for (int j = 0; j < 4; ++j) {
        const int p = (d0 >> 1) + j;
        // inv_freq = 10000^(-p/32); ang = t * inv_freq
        const float invf = exp2f((float)p * -0.41524101186092f); // -log2(1e4)/32
        const float ang  = (float)t * invf;
        float sn, cs;
        sincosf(ang, &sn, &cs);
        const float x1 = f[2 * j], x2 = f[2 * j + 1];
        f[2 * j]     = x1 * cs - x2 * sn;
        f[2 * j + 1] = x2 * cs + x1 * sn;
      }
    }
    float* dst = (part == 0) ? Q : ((part == 1) ? Kx : V);
#pragma unroll
    for (int j = 0; j < 8; ++j) dst[h * 68 + d0 + j] = f[j];
  }
  __syncthreads();

  // scores: lane -> (qh = lane&15, key-group kgp = lane>>4 covering 4 kh)
  const int qh  = lane & 15;
  const int kgp = lane >> 4;
  float s4[4] = {0.f, 0.f, 0.f, 0.f};
  const float* qrow = Q + qh * 68;
#pragma unroll
  for (int d4 = 0; d4 < 64; d4 += 4) {
    const float4 qv = *(const float4*)(qrow + d4);
#pragma unroll
    for (int j = 0; j < 4; ++j) {
      const float4 kv = *(const float4*)(Kx + (kgp * 4 + j) * 68 + d4);
      s4[j] += qv.x * kv.x + qv.y * kv.y + qv.z * kv.z + qv.w * kv.w;
    }
  }
  float mx = -1e30f;
#pragma unroll
  for (int j = 0; j < 4; ++j) { s4[j] *= 0.125f; mx = fmaxf(mx, s4[j]); }
  mx = fmaxf(mx, __shfl_xor(mx, 16, 64));
  mx = fmaxf(mx, __shfl_xor(mx, 32, 64));
  float sum = 0.f;
#pragma unroll
  for (int j = 0; j < 4; ++j) { s4[j] = __expf(s4[j] - mx); sum += s4[j]; }
  sum += __shfl_xor(sum, 16, 64);
  sum += __shfl_xor(sum, 32, 64);
  const float inv = 1.0f / sum;
#pragma unroll
  for (int j = 0; j < 4; ++j) P[(kgp * 4 + j) * 16 + qh] = s4[j] * inv;
  __syncthreads();

  // PV: lane -> (qh, d-group dg = lane>>4, 16 d each)
  const int dg = kgp;
  float o[16];
#pragma unroll
  for (int dd = 0; dd < 16; ++dd) o[dd] = 0.f;
#pragma unroll
  for (int kh = 0; kh < 16; ++kh) {
    const float a = P[kh * 16 + qh];
    const float* vr = V + kh * 68 + dg * 16;
#pragma unroll
    for (int dd = 0; dd < 16; dd += 4) {
      const float4 vv = *(const float4*)(vr + dd);
      o[dd]     += a * vv.x;
      o[dd + 1] += a * vv.y;
      o[dd + 2] += a * vv.z;
      o[dd + 3] += a * vv.w;
    }
  }
  const size_t r = (size_t)b * TT + (size_t)qh * 512 + (t >> 4);
  const int col  = (t & 15) * 64 + dg * 16;
  unsigned short* yp = Y + r * 1024 + col;
  union { uint4 u4; unsigned short s[8]; } o1, o2;
#pragma unroll
  for (int dd = 0; dd < 8; ++dd) o1.s[dd] = f2bf(o[dd]);
#pragma unroll
  for (int dd = 0; dd < 8; ++dd) o2.s[dd] = f2bf(o[8 + dd]);
  ((uint4*)yp)[0] = o1.u4;
  ((uint4*)yp)[1] = o2.u4;
}

// ---------------------------------------------------------------------------
extern "C" void kernel_launch(void* const* d_in, const int* in_sizes, int n_in,
                              void* d_out, int out_size, void* d_ws, size_t ws_size,
                              hipStream_t stream) {
  const float* x    = (const float*)d_in[0];  // (2,8192,1024) fp32
  const float* Wqkv = (const float*)d_in[1];  // (3072,1024)  fp32
  const float* Wout = (const float*)d_in[2];  // (1024,1024)  fp32
  float* out = (float*)d_out;                 // (2,8192,1024) fp32  <-- contract fix

  // workspace: Y 32MiB | qkv chunk 24MiB   (56MiB total)
  unsigned short* Y   = (unsigned short*)d_ws;  // 16384 x 1024 bf16
  unsigned short* qkv = Y + (size_t)BT * 1024;  // MCH x 3072 bf16

  // chunked: qkv = x_chunk @ Wqkv^T, then per-token rope+attention into Y
  for (int base = 0; base < BT; base += MCH) {
    gemm_bt<true, true, false><<<dim3((MCH / 128) * (3072 / 128)), dim3(256), 0, stream>>>(
        x + (size_t)base * 1024, Wqkv, qkv, MCH, 3072, 1024);
    attn_rope_k<<<dim3(MCH / 2), dim3(128), 0, stream>>>(qkv, Y, base);
  }

  // out = Y @ Wout^T : M=16384, N=1024, K=1024  (fp32 output)
  gemm_bt<false, true, true><<<dim3((BT / 128) * (1024 / 128)), dim3(256), 0, stream>>>(
      Y, Wout, out, BT, 1024, 1024);
}

// Round 6
// 376.089 us; speedup vs baseline: 1.2915x; 1.2915x over previous
//
#include <hip/hip_runtime.h>
#include <stdint.h>

#define TT 8192          // sequence length T
#define BT 16384         // B*T tokens
#define MCH 8192         // token chunk for qkv GEMM + attention

typedef __attribute__((ext_vector_type(8))) __bf16 bf16x8;
typedef __attribute__((ext_vector_type(4))) float floatx4;

__device__ __forceinline__ float bf2f(unsigned short h) {
  union { unsigned u; float f; } x; x.u = ((unsigned)h) << 16; return x.f;
}
__device__ __forceinline__ unsigned short f2bf(float f) {
  union { float f; unsigned u; } x; x.f = f;
  unsigned r = (x.u + 0x7fffu + ((x.u >> 16) & 1u)) >> 16;
  return (unsigned short)r;
}
__device__ __forceinline__ void async16(const void* g, void* l) {
  __builtin_amdgcn_global_load_lds(
      (__attribute__((address_space(1))) void*)g,
      (__attribute__((address_space(3))) void*)l, 16, 0, 0);
}

// ---------------------------------------------------------------------------
// fp32 -> bf16 conversion (round-to-nearest-even), float4 vectorized.
// n must be a multiple of 1024 (all our sizes are).
// ---------------------------------------------------------------------------
__global__ __launch_bounds__(256) void cvt_f2b(
    const float* __restrict__ src, unsigned short* __restrict__ dst, int n4) {
  const int i = blockIdx.x * 256 + threadIdx.x;
  if (i < n4) {
    const float4 f = ((const float4*)src)[i];
    union { uint2 u2; unsigned short s[4]; } o;
    o.s[0] = f2bf(f.x); o.s[1] = f2bf(f.y);
    o.s[2] = f2bf(f.z); o.s[3] = f2bf(f.w);
    ((uint2*)dst)[i] = o.u2;
  }
}

// ---------------------------------------------------------------------------
// GEMM: C[M,N] = A[M,K] . W[N,K]^T   (bf16 in; bf16 or fp32 out; fp32 accum)
// m97 structure: 128x128 tile, BK=32, 4 waves (2x2), each wave 64x64 via 4x4
// mfma_f32_16x16x32_bf16; staging via global_load_lds width=16 into
// row-major [128][32] bf16 LDS (b128 fragment reads: uniform 8 acc/bank).
// ---------------------------------------------------------------------------
template <bool CF32>
__global__ __launch_bounds__(256) void gemm_bt(
    const unsigned short* __restrict__ A,
    const unsigned short* __restrict__ W,
    void* __restrict__ C,
    int M, int N, int K)
{
  __shared__ __align__(16) unsigned short As[128 * 32];
  __shared__ __align__(16) unsigned short Bs[128 * 32];

  const int tid  = threadIdx.x;
  const int lane = tid & 63;
  const int w    = tid >> 6;
  const int nb   = N / 128;
  const int bm   = blockIdx.x / nb;
  const int bn   = blockIdx.x % nb;
  const int wm   = w & 1;
  const int wn   = w >> 1;
  const int kg   = lane >> 4;     // k-chunk group 0..3 (8 bf16 each)
  const int lm   = lane & 15;
  const int srow = lane >> 2;     // staging: row within 16-row group
  const int sch  = lane & 3;      // staging: 16B chunk within row

  floatx4 acc[4][4];
  floatx4 z = {0.f, 0.f, 0.f, 0.f};
#pragma unroll
  for (int i = 0; i < 4; ++i)
#pragma unroll
    for (int j = 0; j < 4; ++j) acc[i][j] = z;

  const size_t abase = (size_t)(bm * 128) * K;
  const size_t bbase = (size_t)(bn * 128) * K;

  for (int kt = 0; kt < K; kt += 32) {
#pragma unroll
    for (int s2 = 0; s2 < 2; ++s2) {
      const int s   = 2 * w + s2;          // 16-row group 0..7
      const int row = 16 * s + srow;
      async16(A + abase + (size_t)row * K + kt + sch * 8, (char*)As + s * 1024);
      async16(W + bbase + (size_t)row * K + kt + sch * 8, (char*)Bs + s * 1024);
    }
    __syncthreads();

    bf16x8 af[4], bfr[4];
#pragma unroll
    for (int i = 0; i < 4; ++i) {
      const int r = wm * 64 + i * 16 + lm;
      af[i] = *(const bf16x8*)(As + r * 32 + kg * 8);
    }
#pragma unroll
    for (int j = 0; j < 4; ++j) {
      const int r = wn * 64 + j * 16 + lm;
      bfr[j] = *(const bf16x8*)(Bs + r * 32 + kg * 8);
    }
#pragma unroll
    for (int i = 0; i < 4; ++i)
#pragma unroll
      for (int j = 0; j < 4; ++j)
        acc[i][j] = __builtin_amdgcn_mfma_f32_16x16x32_bf16(af[i], bfr[j], acc[i][j], 0, 0, 0);
    __syncthreads();
  }

  // C/D layout: col = lane&15, row = (lane>>4)*4 + reg
#pragma unroll
  for (int i = 0; i < 4; ++i) {
    const int row0 = bm * 128 + wm * 64 + i * 16 + kg * 4;
#pragma unroll
    for (int j = 0; j < 4; ++j) {
      const int col = bn * 128 + wn * 64 + j * 16 + lm;
#pragma unroll
      for (int r = 0; r < 4; ++r) {
        if (CF32)
          ((float*)C)[(size_t)(row0 + r) * N + col] = acc[i][j][r];
        else
          ((unsigned short*)C)[(size_t)(row0 + r) * N + col] = f2bf(acc[i][j][r]);
      }
    }
  }
}

// ---------------------------------------------------------------------------
// Per-token head-attention with fused RoPE (sin/cos computed inline).
// One wave per token (2 tokens / 128-thread block).
// qkv row (3072 bf16) -> LDS fp32 (stride 68 pads banks), rope on q,k.
// scores 16x16 (scale 1/8) -> softmax -> PV (16x64).
// Output written directly in the transpose(0,2,1,3).reshape layout:
//   Y[b*8192 + qh*512 + t/16][(t&15)*64 + d]
// ---------------------------------------------------------------------------
__global__ __launch_bounds__(128) void attn_rope_k(
    const unsigned short* __restrict__ qkv,   // chunk-local, MCH tokens
    unsigned short* __restrict__ Y,
    int base)                                  // global token offset of chunk
{
  __shared__ float sQ[2][16 * 68];
  __shared__ float sK[2][16 * 68];
  __shared__ float sV[2][16 * 68];
  __shared__ float sP[2][256];   // P^T: [kh*16 + qh]

  const int wave = threadIdx.x >> 6;
  const int lane = threadIdx.x & 63;
  const int ml = blockIdx.x * 2 + wave;  // chunk-local token
  const int m  = base + ml;              // global token
  const int t  = m & (TT - 1);
  const int b  = m >> 13;

  float* Q  = sQ[wave];
  float* Kx = sK[wave];
  float* V  = sV[wave];
  float* P  = sP[wave];

  const uint4* row = (const uint4*)(qkv + (size_t)ml * 3072);
#pragma unroll
  for (int i = 0; i < 6; ++i) {
    const int c = lane + 64 * i;          // chunk of 8 bf16, 0..383
    union { uint4 u4; unsigned short s[8]; } cv;
    cv.u4 = row[c];
    float f[8];
#pragma unroll
    for (int j = 0; j < 8; ++j) f[j] = bf2f(cv.s[j]);
    const int n0   = c * 8;
    const int part = n0 >> 10;            // 0=q 1=k 2=v (uniform per i)
    const int h    = (n0 >> 6) & 15;
    const int d0   = n0 & 63;
    if (part < 2) {
#pragma unroll
      for (int j = 0; j < 4; ++j) {
        const int p = (d0 >> 1) + j;
        const float invf = exp2f((float)p * -0.41524101186092f); // 10000^(-p/32)
        const float ang  = (float)t * invf;
        float sn, cs;
        sincosf(ang, &sn, &cs);
        const float x1 = f[2 * j], x2 = f[2 * j + 1];
        f[2 * j]     = x1 * cs - x2 * sn;
        f[2 * j + 1] = x2 * cs + x1 * sn;
      }
    }
    float* dst = (part == 0) ? Q : ((part == 1) ? Kx : V);
#pragma unroll
    for (int j = 0; j < 8; ++j) dst[h * 68 + d0 + j] = f[j];
  }
  __syncthreads();

  // scores: lane -> (qh = lane&15, key-group kgp = lane>>4 covering 4 kh)
  const int qh  = lane & 15;
  const int kgp = lane >> 4;
  float s4[4] = {0.f, 0.f, 0.f, 0.f};
  const float* qrow = Q + qh * 68;
#pragma unroll
  for (int d4 = 0; d4 < 64; d4 += 4) {
    const float4 qv = *(const float4*)(qrow + d4);
#pragma unroll
    for (int j = 0; j < 4; ++j) {
      const float4 kv = *(const float4*)(Kx + (kgp * 4 + j) * 68 + d4);
      s4[j] += qv.x * kv.x + qv.y * kv.y + qv.z * kv.z + qv.w * kv.w;
    }
  }
  float mx = -1e30f;
#pragma unroll
  for (int j = 0; j < 4; ++j) { s4[j] *= 0.125f; mx = fmaxf(mx, s4[j]); }
  mx = fmaxf(mx, __shfl_xor(mx, 16, 64));
  mx = fmaxf(mx, __shfl_xor(mx, 32, 64));
  float sum = 0.f;
#pragma unroll
  for (int j = 0; j < 4; ++j) { s4[j] = __expf(s4[j] - mx); sum += s4[j]; }
  sum += __shfl_xor(sum, 16, 64);
  sum += __shfl_xor(sum, 32, 64);
  const float inv = 1.0f / sum;
#pragma unroll
  for (int j = 0; j < 4; ++j) P[(kgp * 4 + j) * 16 + qh] = s4[j] * inv;
  __syncthreads();

  // PV: lane -> (qh, d-group dg = lane>>4, 16 d each)
  const int dg = kgp;
  float o[16];
#pragma unroll
  for (int dd = 0; dd < 16; ++dd) o[dd] = 0.f;
#pragma unroll
  for (int kh = 0; kh < 16; ++kh) {
    const float a = P[kh * 16 + qh];
    const float* vr = V + kh * 68 + dg * 16;
#pragma unroll
    for (int dd = 0; dd < 16; dd += 4) {
      const float4 vv = *(const float4*)(vr + dd);
      o[dd]     += a * vv.x;
      o[dd + 1] += a * vv.y;
      o[dd + 2] += a * vv.z;
      o[dd + 3] += a * vv.w;
    }
  }
  const size_t r = (size_t)b * TT + (size_t)qh * 512 + (t >> 4);
  const int col  = (t & 15) * 64 + dg * 16;
  unsigned short* yp = Y + r * 1024 + col;
  union { uint4 u4; unsigned short s[8]; } o1, o2;
#pragma unroll
  for (int dd = 0; dd < 8; ++dd) o1.s[dd] = f2bf(o[dd]);
#pragma unroll
  for (int dd = 0; dd < 8; ++dd) o2.s[dd] = f2bf(o[8 + dd]);
  ((uint4*)yp)[0] = o1.u4;
  ((uint4*)yp)[1] = o2.u4;
}

// ---------------------------------------------------------------------------
extern "C" void kernel_launch(void* const* d_in, const int* in_sizes, int n_in,
                              void* d_out, int out_size, void* d_ws, size_t ws_size,
                              hipStream_t stream) {
  const float* x    = (const float*)d_in[0];  // (2,8192,1024) fp32
  const float* Wqkv = (const float*)d_in[1];  // (3072,1024)  fp32
  const float* Wout = (const float*)d_in[2];  // (1024,1024)  fp32
  float* out = (float*)d_out;                 // (2,8192,1024) fp32

  // ws layout (56 MiB total, proven safe):
  //   Y      16384x1024 bf16  (32 MiB)
  //   Wqkvb   3072x1024 bf16  ( 6 MiB)
  //   Woutb   1024x1024 bf16  ( 2 MiB)
  //   xb      MCH x1024 bf16  (16 MiB)
  // qkv chunk (MCH x 3072 bf16 = 48 MiB) staged in d_out (67 MB),
  // overwritten by the final GEMM after all attention chunks complete.
  unsigned short* Y     = (unsigned short*)d_ws;
  unsigned short* Wqkvb = Y + (size_t)BT * 1024;
  unsigned short* Woutb = Wqkvb + (size_t)3072 * 1024;
  unsigned short* xb    = Woutb + (size_t)1024 * 1024;
  unsigned short* qkvC  = (unsigned short*)d_out;

  cvt_f2b<<<dim3(3072 * 1024 / 4 / 256), dim3(256), 0, stream>>>(Wqkv, Wqkvb, 3072 * 1024 / 4);
  cvt_f2b<<<dim3(1024 * 1024 / 4 / 256), dim3(256), 0, stream>>>(Wout, Woutb, 1024 * 1024 / 4);

  for (int base = 0; base < BT; base += MCH) {
    cvt_f2b<<<dim3(MCH * 1024 / 4 / 256), dim3(256), 0, stream>>>(
        x + (size_t)base * 1024, xb, MCH * 1024 / 4);
    gemm_bt<false><<<dim3((MCH / 128) * (3072 / 128)), dim3(256), 0, stream>>>(
        xb, Wqkvb, qkvC, MCH, 3072, 1024);
    attn_rope_k<<<dim3(MCH / 2), dim3(128), 0, stream>>>(qkvC, Y, base);
  }

  // out = Y @ Wout^T : M=16384, N=1024, K=1024 (fp32 output)
  gemm_bt<true><<<dim3((BT / 128) * (1024 / 128)), dim3(256), 0, stream>>>(
      Y, Woutb, out, BT, 1024, 1024);
}